// Round 1
// baseline (210.624 us; speedup 1.0000x reference)
//
#include <hip/hip_runtime.h>
#include <math.h>

// ---------------------------------------------------------------------------
// StatePerturbationEncoder: gather -> 4x [GEMM(256x256) + GELU] with 3 folded
// BatchNorms. bf16 MFMA (16x16x32), BN folded into next layer's weights.
// ---------------------------------------------------------------------------

typedef __attribute__((ext_vector_type(8))) short short8;   // 8 x bf16 (4 VGPRs)
typedef __attribute__((ext_vector_type(4))) float floatx4;  // MFMA acc

#define NROWS 32768   // B*C = 64*512
#define DDIM  256

__device__ __forceinline__ unsigned short f2bf(float f) {
    // round-to-nearest-even fp32 -> bf16 (finite values only here)
    union { float f; unsigned int u; } v; v.f = f;
    unsigned int r = v.u + 0x7fffu + ((v.u >> 16) & 1u);
    return (unsigned short)(r >> 16);
}

__device__ __forceinline__ float gelu_exact(float x) {
    return 0.5f * x * (1.0f + erff(x * 0.70710678118654752f));
}

__device__ __forceinline__ void load_lds16(const void* g, void* l) {
    // async global->LDS, 16B/lane; LDS dest = wave-uniform base + lane*16
    __builtin_amdgcn_global_load_lds(
        (__attribute__((address_space(1))) void*)(g),
        (__attribute__((address_space(3))) void*)(l),
        16, 0, 0);
}

// ---------------------------------------------------------------------------
// Kernel 1: gather rows of table by ids, cast to bf16 -> X0.
// Extra blocks: transpose+cast W1 -> W1t (N x K), zero stat accumulators.
// ---------------------------------------------------------------------------
__global__ void gather_prep(const int* __restrict__ ids,
                            const float* __restrict__ table,
                            const float* __restrict__ W1,
                            unsigned short* __restrict__ X0,
                            unsigned short* __restrict__ W1t,
                            float* __restrict__ stats /* 1536 floats */)
{
    const int b = blockIdx.x;
    const int t = threadIdx.x;
    if (b < 4096) {                       // 8 rows per block, 32 threads/row
        const int r   = b * 8 + (t >> 5);
        const int lc  = t & 31;
        const int src = ids[r];
        const float4* tp = (const float4*)(table + (size_t)src * DDIM);
        float4 v0 = tp[lc];               // cols 4*lc .. 4*lc+3
        float4 v1 = tp[32 + lc];          // cols 128+4*lc ..
        union { unsigned short u[4]; uint2 v; } o0, o1;
        o0.u[0] = f2bf(v0.x); o0.u[1] = f2bf(v0.y);
        o0.u[2] = f2bf(v0.z); o0.u[3] = f2bf(v0.w);
        o1.u[0] = f2bf(v1.x); o1.u[1] = f2bf(v1.y);
        o1.u[2] = f2bf(v1.z); o1.u[3] = f2bf(v1.w);
        *(uint2*)(X0 + (size_t)r * DDIM + lc * 4)       = o0.v;
        *(uint2*)(X0 + (size_t)r * DDIM + 128 + lc * 4) = o1.v;
        if (b == 0) {
            for (int i = t; i < 1536; i += 256) stats[i] = 0.f;
        }
    } else {                              // blocks 4096..4351: W1 transpose
        const int n = b - 4096;
        W1t[n * DDIM + t] = f2bf(W1[t * DDIM + n]);
    }
}

// ---------------------------------------------------------------------------
// Kernel 2 (x4): C = GELU(A @ W + bias); A: [M][256] bf16 row-major,
// Bt: [256][256] bf16 = W^T (N-major). Optionally accumulate per-column
// sum / sumsq of the GELU output (for the following BatchNorm).
// m97 structure: 128x128 block tile, BK=32, global_load_lds width 16,
// 4 waves each computing 64x64 via 4x4 grid of 16x16x32 MFMAs.
// ---------------------------------------------------------------------------
template<int WRITE_F32, int DO_STATS>
__global__ __launch_bounds__(256, 2)
void gemm_fused(const unsigned short* __restrict__ A,
                const unsigned short* __restrict__ Bt,
                const float* __restrict__ bias,
                void* __restrict__ outp,
                float* __restrict__ statSum,
                float* __restrict__ statSq)
{
    __shared__ alignas(16) unsigned short As[4096];  // [128][32]
    __shared__ alignas(16) unsigned short Bs[4096];  // [128][32]
    __shared__ float colsum[128];
    __shared__ float colsq[128];

    const int tid  = threadIdx.x;
    const int wave = tid >> 6;
    const int lane = tid & 63;
    const int quad = lane >> 4;
    const int l15  = lane & 15;
    const int wm   = wave >> 1;   // wave's 64-row slot (0..1)
    const int wn   = wave & 1;    // wave's 64-col slot (0..1)

    const int m0 = blockIdx.x * 128;
    const int n0 = blockIdx.y * 128;

    // staging: chunk c (16B) covers row c/4 of the [128][32] tile
    const unsigned short* aP0 = A  + (size_t)(m0 +      (tid >> 2)) * DDIM + (tid & 3) * 8;
    const unsigned short* aP1 = A  + (size_t)(m0 + 64 + (tid >> 2)) * DDIM + (tid & 3) * 8;
    const unsigned short* bP0 = Bt + (size_t)(n0 +      (tid >> 2)) * DDIM + (tid & 3) * 8;
    const unsigned short* bP1 = Bt + (size_t)(n0 + 64 + (tid >> 2)) * DDIM + (tid & 3) * 8;
    unsigned short* asD0 = As +        wave * 512;   // wave-uniform LDS bases
    unsigned short* asD1 = As + 2048 + wave * 512;
    unsigned short* bsD0 = Bs +        wave * 512;
    unsigned short* bsD1 = Bs + 2048 + wave * 512;

    floatx4 zero = {0.f, 0.f, 0.f, 0.f};
    floatx4 acc[4][4];
#pragma unroll
    for (int i = 0; i < 4; ++i)
#pragma unroll
        for (int j = 0; j < 4; ++j) acc[i][j] = zero;

    float bias_v[4];
#pragma unroll
    for (int nt = 0; nt < 4; ++nt)
        bias_v[nt] = bias[n0 + wn * 64 + nt * 16 + l15];

    for (int kk = 0; kk < 8; ++kk) {      // K = 256, BK = 32
        __syncthreads();                  // prev iter's frag reads done
        load_lds16(aP0, asD0);
        load_lds16(aP1, asD1);
        load_lds16(bP0, bsD0);
        load_lds16(bP1, bsD1);
        aP0 += 32; aP1 += 32; bP0 += 32; bP1 += 32;
        __syncthreads();                  // drains vmcnt (loads landed)

        short8 af[4], bf[4];
#pragma unroll
        for (int mt = 0; mt < 4; ++mt)
            af[mt] = *(const short8*)(As + (wm * 64 + mt * 16 + l15) * 32 + quad * 8);
#pragma unroll
        for (int nt = 0; nt < 4; ++nt)
            bf[nt] = *(const short8*)(Bs + (wn * 64 + nt * 16 + l15) * 32 + quad * 8);
#pragma unroll
        for (int mt = 0; mt < 4; ++mt)
#pragma unroll
            for (int nt = 0; nt < 4; ++nt)
                acc[mt][nt] = __builtin_amdgcn_mfma_f32_16x16x32_bf16(
                    af[mt], bf[nt], acc[mt][nt], 0, 0, 0);
    }

    // epilogue: bias + GELU + store (+ column stats)
    float s1[4], s2[4];
#pragma unroll
    for (int nt = 0; nt < 4; ++nt) { s1[nt] = 0.f; s2[nt] = 0.f; }

#pragma unroll
    for (int mt = 0; mt < 4; ++mt) {
        const int rowb = m0 + wm * 64 + mt * 16 + quad * 4;  // C/D: row = quad*4+reg
#pragma unroll
        for (int nt = 0; nt < 4; ++nt) {
            const int col = n0 + wn * 64 + nt * 16 + l15;    // C/D: col = lane&15
#pragma unroll
            for (int i = 0; i < 4; ++i) {
                float y = acc[mt][nt][i] + bias_v[nt];
                y = gelu_exact(y);
                if (WRITE_F32) {
                    ((float*)outp)[(size_t)(rowb + i) * DDIM + col] = y;
                } else {
                    ((unsigned short*)outp)[(size_t)(rowb + i) * DDIM + col] = f2bf(y);
                }
                if (DO_STATS) { s1[nt] += y; s2[nt] += y * y; }
            }
        }
    }

    if (DO_STATS) {
#pragma unroll
        for (int nt = 0; nt < 4; ++nt) {   // reduce the 4 quads (same column)
            s1[nt] += __shfl_xor(s1[nt], 16);
            s1[nt] += __shfl_xor(s1[nt], 32);
            s2[nt] += __shfl_xor(s2[nt], 16);
            s2[nt] += __shfl_xor(s2[nt], 32);
        }
        if (tid < 128) { colsum[tid] = 0.f; colsq[tid] = 0.f; }
        __syncthreads();
        if (quad == 0) {
#pragma unroll
            for (int nt = 0; nt < 4; ++nt) {
                const int c = wn * 64 + nt * 16 + l15;
                atomicAdd(&colsum[c], s1[nt]);
                atomicAdd(&colsq[c], s2[nt]);
            }
        }
        __syncthreads();
        if (tid < 128) {
            atomicAdd(&statSum[n0 + tid], colsum[tid]);
            atomicAdd(&statSq[n0 + tid], colsq[tid]);
        }
    }
}

// ---------------------------------------------------------------------------
// Kernel 3 (x3): finalize BN stats and fold the affine into the next layer:
//   scale[k] = rsqrt(var+eps)*gamma[k]; shift[k] = beta[k] - mu[k]*scale[k]
//   Wt'[n][k] = scale[k]*W[k][n] (bf16, transposed);  b'[j] = b[j] + shift@W[:,j]
// ---------------------------------------------------------------------------
__global__ void fold_kernel(const float* __restrict__ sum,
                            const float* __restrict__ sq,
                            const float* __restrict__ g,
                            const float* __restrict__ be,
                            const float* __restrict__ W,
                            const float* __restrict__ b,
                            unsigned short* __restrict__ Wt,
                            float* __restrict__ bOut)
{
    __shared__ float sc[256], sh[256];
    const int t = threadIdx.x;
    const float mu  = sum[t] * (1.0f / 32768.0f);
    const float var = sq[t] * (1.0f / 32768.0f) - mu * mu;
    const float scale = rsqrtf(var + 1e-5f) * g[t];
    sc[t] = scale;
    sh[t] = be[t] - mu * scale;
    __syncthreads();
    if (blockIdx.x < 256) {
        const int n = blockIdx.x;
        Wt[n * DDIM + t] = f2bf(sc[t] * W[t * DDIM + n]);
    } else {
        float acc = b[t];
        for (int k = 0; k < 256; ++k) acc += sh[k] * W[k * DDIM + t];
        bOut[t] = acc;
    }
}

// ---------------------------------------------------------------------------
extern "C" void kernel_launch(void* const* d_in, const int* in_sizes, int n_in,
                              void* d_out, int out_size, void* d_ws, size_t ws_size,
                              hipStream_t stream)
{
    const int*   ids   = (const int*)  d_in[0];
    const float* table = (const float*)d_in[1];
    const float* W[4]  = {(const float*)d_in[2], (const float*)d_in[4],
                          (const float*)d_in[6], (const float*)d_in[8]};
    const float* b[4]  = {(const float*)d_in[3], (const float*)d_in[5],
                          (const float*)d_in[7], (const float*)d_in[9]};
    const float* g[3]  = {(const float*)d_in[10], (const float*)d_in[12], (const float*)d_in[14]};
    const float* be[3] = {(const float*)d_in[11], (const float*)d_in[13], (const float*)d_in[15]};

    unsigned char* ws = (unsigned char*)d_ws;
    unsigned short* buf0 = (unsigned short*)ws;                          // 16 MiB
    unsigned short* buf1 = (unsigned short*)(ws + (size_t)16777216);     // 16 MiB
    unsigned short* W1t  = (unsigned short*)(ws + (size_t)33554432);     // 128 KiB
    unsigned short* Wf0  = (unsigned short*)(ws + (size_t)33685504);
    unsigned short* Wf1  = (unsigned short*)(ws + (size_t)33816576);
    unsigned short* Wf2  = (unsigned short*)(ws + (size_t)33947648);
    float* bf0 = (float*)(ws + (size_t)34078720);
    float* bf1 = (float*)(ws + (size_t)34079744);
    float* bf2 = (float*)(ws + (size_t)34080768);
    float* stats = (float*)(ws + (size_t)34081792);                      // 1536 f32
    float *sum0 = stats,        *sq0 = stats + 256;
    float *sum1 = stats + 512,  *sq1 = stats + 768;
    float *sum2 = stats + 1024, *sq2 = stats + 1280;

    gather_prep<<<4352, 256, 0, stream>>>(ids, table, W[0], buf0, W1t, stats);

    dim3 ggrid(256, 2);  // M/128 x N/128
    gemm_fused<0, 1><<<ggrid, 256, 0, stream>>>(buf0, W1t, b[0], buf1, sum0, sq0);
    fold_kernel<<<257, 256, 0, stream>>>(sum0, sq0, g[0], be[0], W[1], b[1], Wf0, bf0);
    gemm_fused<0, 1><<<ggrid, 256, 0, stream>>>(buf1, Wf0, bf0, buf0, sum1, sq1);
    fold_kernel<<<257, 256, 0, stream>>>(sum1, sq1, g[1], be[1], W[2], b[2], Wf1, bf1);
    gemm_fused<0, 1><<<ggrid, 256, 0, stream>>>(buf0, Wf1, bf1, buf1, sum2, sq2);
    fold_kernel<<<257, 256, 0, stream>>>(sum2, sq2, g[2], be[2], W[3], b[3], Wf2, bf2);
    gemm_fused<1, 0><<<ggrid, 256, 0, stream>>>(buf1, Wf2, bf2, (void*)d_out, nullptr, nullptr);
}

// Round 2
// 191.810 us; speedup vs baseline: 1.0981x; 1.0981x over previous
//
#include <hip/hip_runtime.h>
#include <math.h>

// ---------------------------------------------------------------------------
// StatePerturbationEncoder: gather -> 4x [GEMM(256x256) + GELU] with 3 folded
// BatchNorms. bf16 MFMA (16x16x32), BN folded into next layer's weights.
// R2: tanh-GELU (branchless, ~10 VALU ops vs erff's ~50) + parallel BN-fold
//     (the shift@W matvec was ONE latency-bound block; now block-reduced
//     across the 256 transpose blocks that already read the needed column).
// ---------------------------------------------------------------------------

typedef __attribute__((ext_vector_type(8))) short short8;   // 8 x bf16 (4 VGPRs)
typedef __attribute__((ext_vector_type(4))) float floatx4;  // MFMA acc

#define NROWS 32768   // B*C = 64*512
#define DDIM  256

__device__ __forceinline__ unsigned short f2bf(float f) {
    // round-to-nearest-even fp32 -> bf16 (finite values only here)
    union { float f; unsigned int u; } v; v.f = f;
    unsigned int r = v.u + 0x7fffu + ((v.u >> 16) & 1u);
    return (unsigned short)(r >> 16);
}

__device__ __forceinline__ float gelu_fast(float x) {
    // tanh-approx GELU: 0.5x(1+tanh(0.79788456(x+0.044715x^3)))
    // |err vs exact erf-GELU| ~1e-3 abs; branchless, v_exp + v_rcp.
    float z = 0.7978845608f * (x + 0.044715f * x * x * x);
    float e = __expf(2.0f * z);                 // inf for large z -> handled
    float th = 1.0f - 2.0f * __builtin_amdgcn_rcpf(1.0f + e);
    return 0.5f * x * (1.0f + th);
}

__device__ __forceinline__ void load_lds16(const void* g, void* l) {
    // async global->LDS, 16B/lane; LDS dest = wave-uniform base + lane*16
    __builtin_amdgcn_global_load_lds(
        (__attribute__((address_space(1))) void*)(g),
        (__attribute__((address_space(3))) void*)(l),
        16, 0, 0);
}

// ---------------------------------------------------------------------------
// Kernel 1: gather rows of table by ids, cast to bf16 -> X0.
// Extra blocks: transpose+cast W1 -> W1t (N x K), zero stat accumulators.
// ---------------------------------------------------------------------------
__global__ void gather_prep(const int* __restrict__ ids,
                            const float* __restrict__ table,
                            const float* __restrict__ W1,
                            unsigned short* __restrict__ X0,
                            unsigned short* __restrict__ W1t,
                            float* __restrict__ stats /* 1536 floats */)
{
    const int b = blockIdx.x;
    const int t = threadIdx.x;
    if (b < 4096) {                       // 8 rows per block, 32 threads/row
        const int r   = b * 8 + (t >> 5);
        const int lc  = t & 31;
        const int src = ids[r];
        const float4* tp = (const float4*)(table + (size_t)src * DDIM);
        float4 v0 = tp[lc];               // cols 4*lc .. 4*lc+3
        float4 v1 = tp[32 + lc];          // cols 128+4*lc ..
        union { unsigned short u[4]; uint2 v; } o0, o1;
        o0.u[0] = f2bf(v0.x); o0.u[1] = f2bf(v0.y);
        o0.u[2] = f2bf(v0.z); o0.u[3] = f2bf(v0.w);
        o1.u[0] = f2bf(v1.x); o1.u[1] = f2bf(v1.y);
        o1.u[2] = f2bf(v1.z); o1.u[3] = f2bf(v1.w);
        *(uint2*)(X0 + (size_t)r * DDIM + lc * 4)       = o0.v;
        *(uint2*)(X0 + (size_t)r * DDIM + 128 + lc * 4) = o1.v;
        if (b == 0) {
            for (int i = t; i < 1536; i += 256) stats[i] = 0.f;
        }
    } else {                              // blocks 4096..4351: W1 transpose
        const int n = b - 4096;
        W1t[n * DDIM + t] = f2bf(W1[t * DDIM + n]);
    }
}

// ---------------------------------------------------------------------------
// Kernel 2 (x4): C = GELU(A @ W + bias); A: [M][256] bf16 row-major,
// Bt: [256][256] bf16 = W^T (N-major). Optionally accumulate per-column
// sum / sumsq of the GELU output (for the following BatchNorm).
// m97 structure: 128x128 block tile, BK=32, global_load_lds width 16,
// 4 waves each computing 64x64 via 4x4 grid of 16x16x32 MFMAs.
// ---------------------------------------------------------------------------
template<int WRITE_F32, int DO_STATS>
__global__ __launch_bounds__(256, 2)
void gemm_fused(const unsigned short* __restrict__ A,
                const unsigned short* __restrict__ Bt,
                const float* __restrict__ bias,
                void* __restrict__ outp,
                float* __restrict__ statSum,
                float* __restrict__ statSq)
{
    __shared__ alignas(16) unsigned short As[4096];  // [128][32]
    __shared__ alignas(16) unsigned short Bs[4096];  // [128][32]
    __shared__ float colsum[128];
    __shared__ float colsq[128];

    const int tid  = threadIdx.x;
    const int wave = tid >> 6;
    const int lane = tid & 63;
    const int quad = lane >> 4;
    const int l15  = lane & 15;
    const int wm   = wave >> 1;   // wave's 64-row slot (0..1)
    const int wn   = wave & 1;    // wave's 64-col slot (0..1)

    const int m0 = blockIdx.x * 128;
    const int n0 = blockIdx.y * 128;

    // staging: chunk c (16B) covers row c/4 of the [128][32] tile
    const unsigned short* aP0 = A  + (size_t)(m0 +      (tid >> 2)) * DDIM + (tid & 3) * 8;
    const unsigned short* aP1 = A  + (size_t)(m0 + 64 + (tid >> 2)) * DDIM + (tid & 3) * 8;
    const unsigned short* bP0 = Bt + (size_t)(n0 +      (tid >> 2)) * DDIM + (tid & 3) * 8;
    const unsigned short* bP1 = Bt + (size_t)(n0 + 64 + (tid >> 2)) * DDIM + (tid & 3) * 8;
    unsigned short* asD0 = As +        wave * 512;   // wave-uniform LDS bases
    unsigned short* asD1 = As + 2048 + wave * 512;
    unsigned short* bsD0 = Bs +        wave * 512;
    unsigned short* bsD1 = Bs + 2048 + wave * 512;

    floatx4 zero = {0.f, 0.f, 0.f, 0.f};
    floatx4 acc[4][4];
#pragma unroll
    for (int i = 0; i < 4; ++i)
#pragma unroll
        for (int j = 0; j < 4; ++j) acc[i][j] = zero;

    float bias_v[4];
#pragma unroll
    for (int nt = 0; nt < 4; ++nt)
        bias_v[nt] = bias[n0 + wn * 64 + nt * 16 + l15];

    for (int kk = 0; kk < 8; ++kk) {      // K = 256, BK = 32
        __syncthreads();                  // prev iter's frag reads done
        load_lds16(aP0, asD0);
        load_lds16(aP1, asD1);
        load_lds16(bP0, bsD0);
        load_lds16(bP1, bsD1);
        aP0 += 32; aP1 += 32; bP0 += 32; bP1 += 32;
        __syncthreads();                  // drains vmcnt (loads landed)

        short8 af[4], bf[4];
#pragma unroll
        for (int mt = 0; mt < 4; ++mt)
            af[mt] = *(const short8*)(As + (wm * 64 + mt * 16 + l15) * 32 + quad * 8);
#pragma unroll
        for (int nt = 0; nt < 4; ++nt)
            bf[nt] = *(const short8*)(Bs + (wn * 64 + nt * 16 + l15) * 32 + quad * 8);
#pragma unroll
        for (int mt = 0; mt < 4; ++mt)
#pragma unroll
            for (int nt = 0; nt < 4; ++nt)
                acc[mt][nt] = __builtin_amdgcn_mfma_f32_16x16x32_bf16(
                    af[mt], bf[nt], acc[mt][nt], 0, 0, 0);
    }

    // epilogue: bias + GELU + store (+ column stats)
    float s1[4], s2[4];
#pragma unroll
    for (int nt = 0; nt < 4; ++nt) { s1[nt] = 0.f; s2[nt] = 0.f; }

#pragma unroll
    for (int mt = 0; mt < 4; ++mt) {
        const int rowb = m0 + wm * 64 + mt * 16 + quad * 4;  // C/D: row = quad*4+reg
#pragma unroll
        for (int nt = 0; nt < 4; ++nt) {
            const int col = n0 + wn * 64 + nt * 16 + l15;    // C/D: col = lane&15
#pragma unroll
            for (int i = 0; i < 4; ++i) {
                float y = acc[mt][nt][i] + bias_v[nt];
                y = gelu_fast(y);
                if (WRITE_F32) {
                    ((float*)outp)[(size_t)(rowb + i) * DDIM + col] = y;
                } else {
                    ((unsigned short*)outp)[(size_t)(rowb + i) * DDIM + col] = f2bf(y);
                }
                if (DO_STATS) { s1[nt] += y; s2[nt] += y * y; }
            }
        }
    }

    if (DO_STATS) {
#pragma unroll
        for (int nt = 0; nt < 4; ++nt) {   // reduce the 4 quads (same column)
            s1[nt] += __shfl_xor(s1[nt], 16);
            s1[nt] += __shfl_xor(s1[nt], 32);
            s2[nt] += __shfl_xor(s2[nt], 16);
            s2[nt] += __shfl_xor(s2[nt], 32);
        }
        if (tid < 128) { colsum[tid] = 0.f; colsq[tid] = 0.f; }
        __syncthreads();
        if (quad == 0) {
#pragma unroll
            for (int nt = 0; nt < 4; ++nt) {
                const int c = wn * 64 + nt * 16 + l15;
                atomicAdd(&colsum[c], s1[nt]);
                atomicAdd(&colsq[c], s2[nt]);
            }
        }
        __syncthreads();
        if (tid < 128) {
            atomicAdd(&statSum[n0 + tid], colsum[tid]);
            atomicAdd(&statSq[n0 + tid], colsq[tid]);
        }
    }
}

// ---------------------------------------------------------------------------
// Kernel 3 (x3): finalize BN stats and fold the affine into the next layer:
//   scale[k] = rsqrt(var+eps)*gamma[k]; shift[k] = beta[k] - mu[k]*scale[k]
//   Wt'[n][k] = scale[k]*W[k][n] (bf16, transposed);  b'[n] = b[n] + shift@W[:,n]
// Block n reads column n of W once and uses it for BOTH outputs (the old
// version had the b' matvec in a single serial block - ~12us of latency).
// ---------------------------------------------------------------------------
__global__ void fold_kernel(const float* __restrict__ sum,
                            const float* __restrict__ sq,
                            const float* __restrict__ g,
                            const float* __restrict__ be,
                            const float* __restrict__ W,
                            const float* __restrict__ b,
                            unsigned short* __restrict__ Wt,
                            float* __restrict__ bOut)
{
    __shared__ float sc[256], sh[256], red[4];
    const int t = threadIdx.x;
    const int n = blockIdx.x;
    const float mu  = sum[t] * (1.0f / 32768.0f);
    const float var = sq[t] * (1.0f / 32768.0f) - mu * mu;
    const float scale = rsqrtf(var + 1e-5f) * g[t];
    sc[t] = scale;
    sh[t] = be[t] - mu * scale;
    __syncthreads();
    const float w = W[t * DDIM + n];          // column n of W
    Wt[n * DDIM + t] = f2bf(sc[t] * w);
    float p = sh[t] * w;                      // partial of shift @ W[:,n]
#pragma unroll
    for (int o = 32; o; o >>= 1) p += __shfl_down(p, o);   // wave64 reduce
    if ((t & 63) == 0) red[t >> 6] = p;
    __syncthreads();
    if (t == 0) bOut[n] = b[n] + red[0] + red[1] + red[2] + red[3];
}

// ---------------------------------------------------------------------------
extern "C" void kernel_launch(void* const* d_in, const int* in_sizes, int n_in,
                              void* d_out, int out_size, void* d_ws, size_t ws_size,
                              hipStream_t stream)
{
    const int*   ids   = (const int*)  d_in[0];
    const float* table = (const float*)d_in[1];
    const float* W[4]  = {(const float*)d_in[2], (const float*)d_in[4],
                          (const float*)d_in[6], (const float*)d_in[8]};
    const float* b[4]  = {(const float*)d_in[3], (const float*)d_in[5],
                          (const float*)d_in[7], (const float*)d_in[9]};
    const float* g[3]  = {(const float*)d_in[10], (const float*)d_in[12], (const float*)d_in[14]};
    const float* be[3] = {(const float*)d_in[11], (const float*)d_in[13], (const float*)d_in[15]};

    unsigned char* ws = (unsigned char*)d_ws;
    unsigned short* buf0 = (unsigned short*)ws;                          // 16 MiB
    unsigned short* buf1 = (unsigned short*)(ws + (size_t)16777216);     // 16 MiB
    unsigned short* W1t  = (unsigned short*)(ws + (size_t)33554432);     // 128 KiB
    unsigned short* Wf0  = (unsigned short*)(ws + (size_t)33685504);
    unsigned short* Wf1  = (unsigned short*)(ws + (size_t)33816576);
    unsigned short* Wf2  = (unsigned short*)(ws + (size_t)33947648);
    float* bf0 = (float*)(ws + (size_t)34078720);
    float* bf1 = (float*)(ws + (size_t)34079744);
    float* bf2 = (float*)(ws + (size_t)34080768);
    float* stats = (float*)(ws + (size_t)34081792);                      // 1536 f32
    float *sum0 = stats,        *sq0 = stats + 256;
    float *sum1 = stats + 512,  *sq1 = stats + 768;
    float *sum2 = stats + 1024, *sq2 = stats + 1280;

    gather_prep<<<4352, 256, 0, stream>>>(ids, table, W[0], buf0, W1t, stats);

    dim3 ggrid(256, 2);  // M/128 x N/128
    gemm_fused<0, 1><<<ggrid, 256, 0, stream>>>(buf0, W1t, b[0], buf1, sum0, sq0);
    fold_kernel<<<256, 256, 0, stream>>>(sum0, sq0, g[0], be[0], W[1], b[1], Wf0, bf0);
    gemm_fused<0, 1><<<ggrid, 256, 0, stream>>>(buf1, Wf0, bf0, buf0, sum1, sq1);
    fold_kernel<<<256, 256, 0, stream>>>(sum1, sq1, g[1], be[1], W[2], b[2], Wf1, bf1);
    gemm_fused<0, 1><<<ggrid, 256, 0, stream>>>(buf0, Wf1, bf1, buf1, sum2, sq2);
    fold_kernel<<<256, 256, 0, stream>>>(sum2, sq2, g[2], be[2], W[3], b[3], Wf2, bf2);
    gemm_fused<1, 0><<<ggrid, 256, 0, stream>>>(buf1, Wf2, bf2, (void*)d_out, nullptr, nullptr);
}